// Round 1
// baseline (1219.710 us; speedup 1.0000x reference)
//
#include <hip/hip_runtime.h>
#include <math.h>

#define BN_EPS 1e-5f
#define SLOPE 0.01f

__device__ __constant__ int c_g16_st[16] = {0,5,8,11,14,17,20,25,30,35,46,49,52,55,58,61};
__device__ __constant__ int c_g16_n[16]  = {5,3,3,3,3,3,5,5,5,11,3,3,3,3,3,12};
__device__ __constant__ int c_g7_st[7]   = {0,5,14,23,48,57,66};
__device__ __constant__ int c_g7_n[7]    = {5,9,9,25,9,9,12};

__device__ __forceinline__ float lrelu(float y) { return y > 0.f ? y : SLOPE * y; }

// meso helper: G teams of T lanes each, group k -> cat[b*735 + BASE + g*G + k]
template<int T, int G, int BASE>
__device__ void meso_part(const int* __restrict__ st_arr, const int* __restrict__ n_arr,
                          int lane, long b, const float* h, const int* __restrict__ idxa,
                          const float* mw, float* fwbuf, float* scbuf,
                          float* __restrict__ catb)
{
  const int team = lane / T, slot = lane - team * T;
  int st = 0, n = 0;
  if (team < G) { st = st_arr[team]; n = n_arr[team]; }
  float sp[10] = {0,0,0,0,0,0,0,0,0,0};
  if (team < G) {
    for (int j = slot; j < n; j += T) {
      int ri = idxa[st + j];
      float sv[5];
      #pragma unroll
      for (int g = 0; g < 5; ++g) sv[g] = h[ri*8 + g];
      #pragma unroll
      for (int t = 0; t < 10; ++t) {
        float f = sv[0]*mw[t] + sv[1]*mw[10+t] + sv[2]*mw[20+t] + sv[3]*mw[30+t] + sv[4]*mw[40+t];
        fwbuf[(st+j)*10 + t] = f;
        sp[t] += f;
      }
    }
  }
  #pragma unroll
  for (int off = 1; off < T; off <<= 1) {
    #pragma unroll
    for (int t = 0; t < 10; ++t) sp[t] += __shfl_xor(sp[t], off);
  }
  __syncthreads();
  if (team < G) {
    for (int j = slot; j < n; j += T) {
      float sc = 0.f;
      #pragma unroll
      for (int t = 0; t < 10; ++t) sc += fwbuf[(st+j)*10 + t] * sp[t];
      scbuf[st + j] = sc;
    }
  }
  __syncthreads();
  float po[5] = {0,0,0,0,0};
  if (team < G) {
    float mx = -1e30f;
    for (int jj = 0; jj < n; ++jj) mx = fmaxf(mx, scbuf[st + jj]);
    float sum = 0.f;
    for (int jj = 0; jj < n; ++jj) sum += expf(scbuf[st + jj] - mx);
    float inv = 1.f / sum;
    for (int j = slot; j < n; j += T) {
      float a = expf(scbuf[st + j] - mx) * inv;
      int ri = idxa[st + j];
      #pragma unroll
      for (int g = 0; g < 5; ++g) po[g] += a * h[ri*8 + g];
    }
  }
  #pragma unroll
  for (int off = 1; off < T; off <<= 1) {
    #pragma unroll
    for (int g = 0; g < 5; ++g) po[g] += __shfl_xor(po[g], off);
  }
  if (team < G && slot == 0) {
    #pragma unroll
    for (int g = 0; g < 5; ++g) catb[b*735 + BASE + g*G + team] = po[g];
  }
}

// one wave (64 lanes) per sample; 4 samples per block
__global__ __launch_bounds__(256) void front_kernel(
    const float* __restrict__ x, const float* __restrict__ adj,
    const float* __restrict__ lgcn_w, const float* __restrict__ lgcn_b,
    const float* __restrict__ ca1_w1, const float* __restrict__ ca1_w2,
    const float* __restrict__ ca2_w1, const float* __restrict__ ca2_w2,
    const float* __restrict__ meso1_w, const float* __restrict__ meso2_w,
    const int* __restrict__ idx16, const int* __restrict__ idx7,
    float* __restrict__ catb, float* __restrict__ outp, int B)
{
  __shared__ __align__(16) float adjT[62*65];
  __shared__ __align__(16) float wf_s[4][496];   // [62][8] padded
  __shared__ __align__(16) float h_s[4][496];    // residual, [62][8] padded
  __shared__ __align__(16) float fw_s[4][800];   // up to 78 rows x 10
  __shared__ float sc_s[4][80];
  __shared__ float t_s[4][64];                   // mlp hidden (avg|max)
  __shared__ float small_s[4][16];               // avg[5], mx[5], att1[5]
  __shared__ float v62_s[4][192];                // avg2[62], mx2[62](+64), att2[62](+128)
  __shared__ float mw_s[100];                    // meso1_w | meso2_w

  const int tid = threadIdx.x;
  const int w = tid >> 6;
  const int lane = tid & 63;
  const long b = (long)blockIdx.x * 4 + w;

  // stage adj transposed: adjT[j*65+i] = adj[i][j]  (coalesced read, conflict-free write)
  for (int t = tid; t < 62*62; t += 256) {
    int i = t / 62, j = t - i*62;
    adjT[j*65 + i] = adj[t];
  }
  if (tid < 50) mw_s[tid] = meso1_w[tid];
  else if (tid < 100) mw_s[tid] = meso2_w[tid - 50];
  __syncthreads();

  const float* xr = x + b * 310;
  // wf[i][d] = sum_j x[b, j*62+i] * lgcn_w[j][d]
  if (lane < 62) {
    float wf[5] = {0,0,0,0,0};
    #pragma unroll
    for (int j = 0; j < 5; ++j) {
      float xv = xr[j*62 + lane];
      #pragma unroll
      for (int d = 0; d < 5; ++d) wf[d] += xv * lgcn_w[j*5 + d];
    }
    #pragma unroll
    for (int d = 0; d < 5; ++d) wf_s[w][lane*8 + d] = wf[d];
  }
  __syncthreads();
  // h[i][d] = sum_j adj[i][j]*wf[j][d] + lgcn_b[d]   (residual)
  if (lane < 62) {
    float acc[5];
    #pragma unroll
    for (int d = 0; d < 5; ++d) acc[d] = lgcn_b[d];
    for (int j = 0; j < 62; ++j) {
      float a = adjT[j*65 + lane];
      float4 w4 = *(const float4*)&wf_s[w][j*8];
      float w5 = wf_s[w][j*8 + 4];
      acc[0] += a*w4.x; acc[1] += a*w4.y; acc[2] += a*w4.z; acc[3] += a*w4.w; acc[4] += a*w5;
    }
    #pragma unroll
    for (int d = 0; d < 5; ++d) h_s[w][lane*8 + d] = acc[d];
  }
  __syncthreads();
  // x_flat part of cat + CA1 avg/max (over i, per d)
  for (int p = lane; p < 310; p += 64) {
    int d = p / 62, i = p - d*62;
    catb[b*735 + p] = h_s[w][i*8 + d];
  }
  if (lane < 5) {
    float s = 0.f, m = -1e30f;
    for (int i = 0; i < 62; ++i) { float v = h_s[w][i*8 + lane]; s += v; m = fmaxf(m, v); }
    small_s[w][lane] = s * (1.f/62.f);
    small_s[w][5 + lane] = m;
  }
  __syncthreads();
  // CA1 mlp hidden
  if (lane < 32) {
    float ta = 0.f, tm = 0.f;
    #pragma unroll
    for (int d = 0; d < 5; ++d) {
      float wv = ca1_w1[lane*5 + d];
      ta += small_s[w][d] * wv;
      tm += small_s[w][5 + d] * wv;
    }
    t_s[w][lane] = fmaxf(ta, 0.f);
    t_s[w][32 + lane] = fmaxf(tm, 0.f);
  }
  __syncthreads();
  // att1
  if (lane < 5) {
    float sa = 0.f, sm = 0.f;
    for (int o = 0; o < 32; ++o) {
      float wv = ca1_w2[lane*32 + o];
      sa += t_s[w][o] * wv; sm += t_s[w][32 + o] * wv;
    }
    float a = 1.f / (1.f + expf(-(sa + sm)));
    small_s[w][10 + lane] = a;
    outp[(long)B*64 + b*5 + lane] = a;
  }
  __syncthreads();
  // CA2 avg/max (over d, per i) on out1 = h*(1+att1[d])
  if (lane < 62) {
    float s = 0.f, m = -1e30f;
    #pragma unroll
    for (int d = 0; d < 5; ++d) {
      float v = h_s[w][lane*8 + d] * (1.f + small_s[w][10 + d]);
      s += v; m = fmaxf(m, v);
    }
    v62_s[w][lane] = s * (1.f/5.f);
    v62_s[w][64 + lane] = m;
  }
  __syncthreads();
  // CA2 mlp hidden
  if (lane < 32) {
    float ta = 0.f, tm = 0.f;
    for (int i = 0; i < 62; ++i) {
      float wv = ca2_w1[lane*62 + i];
      ta += v62_s[w][i] * wv; tm += v62_s[w][64 + i] * wv;
    }
    t_s[w][lane] = fmaxf(ta, 0.f);
    t_s[w][32 + lane] = fmaxf(tm, 0.f);
  }
  __syncthreads();
  // att2
  if (lane < 62) {
    float sa = 0.f, sm = 0.f;
    for (int o = 0; o < 32; ++o) {
      float wv = ca2_w2[lane*32 + o];
      sa += t_s[w][o] * wv; sm += t_s[w][32 + o] * wv;
    }
    float a = 1.f / (1.f + expf(-(sa + sm)));
    v62_s[w][128 + lane] = a;
    outp[(long)B*69 + b*62 + lane] = a;
  }
  __syncthreads();
  // out_flat part of cat
  for (int p = lane; p < 310; p += 64) {
    int d = p / 62, i = p - d*62;
    catb[b*735 + 310 + p] = h_s[w][i*8 + d] * (1.f + small_s[w][10 + d]) * (1.f + v62_s[w][128 + i]);
  }
  __syncthreads();
  // meso1: 16 teams x 4 lanes, base 620, stride 16
  meso_part<4,16,620>(c_g16_st, c_g16_n, lane, b, h_s[w], idx16, mw_s, fw_s[w], sc_s[w], catb);
  __syncthreads();
  // meso2: 7 teams x 8 lanes, base 700, stride 7
  meso_part<8,7,700>(c_g7_st, c_g7_n, lane, b, h_s[w], idx7, mw_s + 50, fw_s[w], sc_s[w], catb);
}

// fused 3-layer MLP + BN + leaky-relu; 32 samples per block, 256 threads
__global__ __launch_bounds__(256) void mlp_kernel(
    const float* __restrict__ catb,
    const float* __restrict__ w1, const float* __restrict__ b1,
    const float* __restrict__ g1, const float* __restrict__ be1,
    const float* __restrict__ m1, const float* __restrict__ v1,
    const float* __restrict__ w2, const float* __restrict__ b2,
    const float* __restrict__ g2, const float* __restrict__ be2,
    const float* __restrict__ m2, const float* __restrict__ v2,
    const float* __restrict__ w3, const float* __restrict__ b3,
    const float* __restrict__ g3, const float* __restrict__ be3,
    const float* __restrict__ m3, const float* __restrict__ v3,
    float* __restrict__ outp)
{
  __shared__ __align__(16) float a_lds[32][64];
  __shared__ __align__(16) float y1_lds[32][264];
  __shared__ __align__(16) float y2_lds[32][132];

  const int tid = threadIdx.x;
  const long b0 = (long)blockIdx.x * 32;

  // ---- layer 1: (32x735)@(735x256)
  const int tc = tid & 63;   // cols tc*4 .. tc*4+3
  const int tr = tid >> 6;   // rows tr*8 .. tr*8+7
  float acc[8][4];
  #pragma unroll
  for (int r = 0; r < 8; ++r) { acc[r][0]=0.f; acc[r][1]=0.f; acc[r][2]=0.f; acc[r][3]=0.f; }

  for (int kc = 0; kc < 735; kc += 64) {
    const int len = (735 - kc) < 64 ? (735 - kc) : 64;
    __syncthreads();
    for (int t = tid; t < 32*64; t += 256) {
      int r = t >> 6, k = t & 63;
      a_lds[r][k] = (k < len) ? catb[(b0 + r)*735 + kc + k] : 0.f;
    }
    __syncthreads();
    if (len == 64) {
      #pragma unroll 4
      for (int k = 0; k < 64; ++k) {
        float4 wv = *(const float4*)&w1[(long)(kc + k)*256 + tc*4];
        #pragma unroll
        for (int r = 0; r < 8; ++r) {
          float a = a_lds[tr*8 + r][k];
          acc[r][0] += a*wv.x; acc[r][1] += a*wv.y; acc[r][2] += a*wv.z; acc[r][3] += a*wv.w;
        }
      }
    } else {
      for (int k = 0; k < len; ++k) {
        float4 wv = *(const float4*)&w1[(long)(kc + k)*256 + tc*4];
        #pragma unroll
        for (int r = 0; r < 8; ++r) {
          float a = a_lds[tr*8 + r][k];
          acc[r][0] += a*wv.x; acc[r][1] += a*wv.y; acc[r][2] += a*wv.z; acc[r][3] += a*wv.w;
        }
      }
    }
  }
  {
    int c = tc * 4;
    float4 bb = *(const float4*)&b1[c];
    float4 mm = *(const float4*)&m1[c];
    float4 vv = *(const float4*)&v1[c];
    float4 gg = *(const float4*)&g1[c];
    float4 ee = *(const float4*)&be1[c];
    float s0 = gg.x * rsqrtf(vv.x + BN_EPS), s1 = gg.y * rsqrtf(vv.y + BN_EPS);
    float s2 = gg.z * rsqrtf(vv.z + BN_EPS), s3 = gg.w * rsqrtf(vv.w + BN_EPS);
    #pragma unroll
    for (int r = 0; r < 8; ++r) {
      int row = tr*8 + r;
      y1_lds[row][c+0] = lrelu((acc[r][0] + bb.x - mm.x)*s0 + ee.x);
      y1_lds[row][c+1] = lrelu((acc[r][1] + bb.y - mm.y)*s1 + ee.y);
      y1_lds[row][c+2] = lrelu((acc[r][2] + bb.z - mm.z)*s2 + ee.z);
      y1_lds[row][c+3] = lrelu((acc[r][3] + bb.w - mm.w)*s3 + ee.w);
    }
  }
  __syncthreads();

  // ---- layer 2: (32x256)@(256x128)
  const int tc2 = tid & 31;  // cols tc2*4
  const int tr2 = tid >> 5;  // rows tr2*4 .. +3
  float acc2[4][4];
  #pragma unroll
  for (int r = 0; r < 4; ++r) { acc2[r][0]=0.f; acc2[r][1]=0.f; acc2[r][2]=0.f; acc2[r][3]=0.f; }
  #pragma unroll 4
  for (int k = 0; k < 256; ++k) {
    float4 wv = *(const float4*)&w2[k*128 + tc2*4];
    #pragma unroll
    for (int r = 0; r < 4; ++r) {
      float a = y1_lds[tr2*4 + r][k];
      acc2[r][0] += a*wv.x; acc2[r][1] += a*wv.y; acc2[r][2] += a*wv.z; acc2[r][3] += a*wv.w;
    }
  }
  {
    int c = tc2 * 4;
    float4 bb = *(const float4*)&b2[c];
    float4 mm = *(const float4*)&m2[c];
    float4 vv = *(const float4*)&v2[c];
    float4 gg = *(const float4*)&g2[c];
    float4 ee = *(const float4*)&be2[c];
    float s0 = gg.x * rsqrtf(vv.x + BN_EPS), s1 = gg.y * rsqrtf(vv.y + BN_EPS);
    float s2 = gg.z * rsqrtf(vv.z + BN_EPS), s3 = gg.w * rsqrtf(vv.w + BN_EPS);
    #pragma unroll
    for (int r = 0; r < 4; ++r) {
      int row = tr2*4 + r;
      y2_lds[row][c+0] = lrelu((acc2[r][0] + bb.x - mm.x)*s0 + ee.x);
      y2_lds[row][c+1] = lrelu((acc2[r][1] + bb.y - mm.y)*s1 + ee.y);
      y2_lds[row][c+2] = lrelu((acc2[r][2] + bb.z - mm.z)*s2 + ee.z);
      y2_lds[row][c+3] = lrelu((acc2[r][3] + bb.w - mm.w)*s3 + ee.w);
    }
  }
  __syncthreads();

  // ---- layer 3: (32x128)@(128x64)
  const int tc3 = tid & 15;  // cols tc3*4
  const int tr3 = tid >> 4;  // rows tr3*2 .. +1
  float acc3[2][4];
  #pragma unroll
  for (int r = 0; r < 2; ++r) { acc3[r][0]=0.f; acc3[r][1]=0.f; acc3[r][2]=0.f; acc3[r][3]=0.f; }
  #pragma unroll 4
  for (int k = 0; k < 128; ++k) {
    float4 wv = *(const float4*)&w3[k*64 + tc3*4];
    #pragma unroll
    for (int r = 0; r < 2; ++r) {
      float a = y2_lds[tr3*2 + r][k];
      acc3[r][0] += a*wv.x; acc3[r][1] += a*wv.y; acc3[r][2] += a*wv.z; acc3[r][3] += a*wv.w;
    }
  }
  {
    int c = tc3 * 4;
    float4 bb = *(const float4*)&b3[c];
    float4 mm = *(const float4*)&m3[c];
    float4 vv = *(const float4*)&v3[c];
    float4 gg = *(const float4*)&g3[c];
    float4 ee = *(const float4*)&be3[c];
    float s0 = gg.x * rsqrtf(vv.x + BN_EPS), s1 = gg.y * rsqrtf(vv.y + BN_EPS);
    float s2 = gg.z * rsqrtf(vv.z + BN_EPS), s3 = gg.w * rsqrtf(vv.w + BN_EPS);
    #pragma unroll
    for (int r = 0; r < 2; ++r) {
      int row = tr3*2 + r;
      float4 o;
      o.x = lrelu((acc3[r][0] + bb.x - mm.x)*s0 + ee.x);
      o.y = lrelu((acc3[r][1] + bb.y - mm.y)*s1 + ee.y);
      o.z = lrelu((acc3[r][2] + bb.z - mm.z)*s2 + ee.z);
      o.w = lrelu((acc3[r][3] + bb.w - mm.w)*s3 + ee.w);
      *(float4*)&outp[(b0 + row)*64 + c] = o;
    }
  }
}

extern "C" void kernel_launch(void* const* d_in, const int* in_sizes, int n_in,
                              void* d_out, int out_size, void* d_ws, size_t ws_size,
                              hipStream_t stream) {
  const float* x       = (const float*)d_in[0];
  const float* adj     = (const float*)d_in[1];
  const float* lgcn_w  = (const float*)d_in[2];
  const float* lgcn_b  = (const float*)d_in[3];
  const float* ca1_w1  = (const float*)d_in[4];
  const float* ca1_w2  = (const float*)d_in[5];
  const float* ca2_w1  = (const float*)d_in[6];
  const float* ca2_w2  = (const float*)d_in[7];
  const float* meso1_w = (const float*)d_in[8];
  const float* meso2_w = (const float*)d_in[9];
  const int*   idx16   = (const int*)d_in[10];
  const int*   idx7    = (const int*)d_in[11];
  const float* w1 = (const float*)d_in[12];
  const float* b1 = (const float*)d_in[13];
  const float* w2 = (const float*)d_in[14];
  const float* b2 = (const float*)d_in[15];
  const float* w3 = (const float*)d_in[16];
  const float* b3 = (const float*)d_in[17];
  const float* g1 = (const float*)d_in[18];
  const float* be1= (const float*)d_in[19];
  const float* m1 = (const float*)d_in[20];
  const float* v1 = (const float*)d_in[21];
  const float* g2 = (const float*)d_in[22];
  const float* be2= (const float*)d_in[23];
  const float* m2 = (const float*)d_in[24];
  const float* v2 = (const float*)d_in[25];
  const float* g3 = (const float*)d_in[26];
  const float* be3= (const float*)d_in[27];
  const float* m3 = (const float*)d_in[28];
  const float* v3 = (const float*)d_in[29];

  const int B = in_sizes[0] / 310;
  float* catb = (float*)d_ws;
  if (ws_size < (size_t)B * 735 * sizeof(float)) return;  // ws too small: fail visibly

  front_kernel<<<B/4, 256, 0, stream>>>(x, adj, lgcn_w, lgcn_b, ca1_w1, ca1_w2,
                                        ca2_w1, ca2_w2, meso1_w, meso2_w,
                                        idx16, idx7, catb, (float*)d_out, B);
  mlp_kernel<<<B/32, 256, 0, stream>>>(catb, w1, b1, g1, be1, m1, v1,
                                       w2, b2, g2, be2, m2, v2,
                                       w3, b3, g3, be3, m3, v3, (float*)d_out);
}

// Round 2
// 702.019 us; speedup vs baseline: 1.7374x; 1.7374x over previous
//
#include <hip/hip_runtime.h>
#include <math.h>

#define BN_EPS 1e-5f
#define SLOPE 0.01f

typedef _Float16 f16;
typedef _Float16 f16x8 __attribute__((ext_vector_type(8)));
typedef float f32x4 __attribute__((ext_vector_type(4)));

__device__ __constant__ int c_g16_st[16] = {0,5,8,11,14,17,20,25,30,35,46,49,52,55,58,61};
__device__ __constant__ int c_g16_n[16]  = {5,3,3,3,3,3,5,5,5,11,3,3,3,3,3,12};
__device__ __constant__ int c_g7_st[7]   = {0,5,14,23,48,57,66};
__device__ __constant__ int c_g7_n[7]    = {5,9,9,25,9,9,12};

__device__ __forceinline__ float lrelu(float y) { return y > 0.f ? y : SLOPE * y; }

// meso helper: G teams of T lanes each, group k -> cat[b*736 + BASE + g*G + k]
template<int T, int G, int BASE>
__device__ void meso_part(const int* __restrict__ st_arr, const int* __restrict__ n_arr,
                          int lane, long b, const float* h, const int* __restrict__ idxa,
                          const float* mw, float* fwbuf, float* scbuf,
                          f16* __restrict__ catb)
{
  const int team = lane / T, slot = lane - team * T;
  int st = 0, n = 0;
  if (team < G) { st = st_arr[team]; n = n_arr[team]; }
  float sp[10] = {0,0,0,0,0,0,0,0,0,0};
  if (team < G) {
    for (int j = slot; j < n; j += T) {
      int ri = idxa[st + j];
      float sv[5];
      #pragma unroll
      for (int g = 0; g < 5; ++g) sv[g] = h[ri*8 + g];
      #pragma unroll
      for (int t = 0; t < 10; ++t) {
        float f = sv[0]*mw[t] + sv[1]*mw[10+t] + sv[2]*mw[20+t] + sv[3]*mw[30+t] + sv[4]*mw[40+t];
        fwbuf[(st+j)*10 + t] = f;
        sp[t] += f;
      }
    }
  }
  #pragma unroll
  for (int off = 1; off < T; off <<= 1) {
    #pragma unroll
    for (int t = 0; t < 10; ++t) sp[t] += __shfl_xor(sp[t], off);
  }
  __syncthreads();
  if (team < G) {
    for (int j = slot; j < n; j += T) {
      float sc = 0.f;
      #pragma unroll
      for (int t = 0; t < 10; ++t) sc += fwbuf[(st+j)*10 + t] * sp[t];
      scbuf[st + j] = sc;
    }
  }
  __syncthreads();
  float po[5] = {0,0,0,0,0};
  if (team < G) {
    float mx = -1e30f;
    for (int jj = 0; jj < n; ++jj) mx = fmaxf(mx, scbuf[st + jj]);
    float sum = 0.f;
    for (int jj = 0; jj < n; ++jj) sum += expf(scbuf[st + jj] - mx);
    float inv = 1.f / sum;
    for (int j = slot; j < n; j += T) {
      float a = expf(scbuf[st + j] - mx) * inv;
      int ri = idxa[st + j];
      #pragma unroll
      for (int g = 0; g < 5; ++g) po[g] += a * h[ri*8 + g];
    }
  }
  #pragma unroll
  for (int off = 1; off < T; off <<= 1) {
    #pragma unroll
    for (int g = 0; g < 5; ++g) po[g] += __shfl_xor(po[g], off);
  }
  if (team < G && slot == 0) {
    #pragma unroll
    for (int g = 0; g < 5; ++g) catb[b*736 + BASE + g*G + team] = (f16)po[g];
  }
}

// one wave (64 lanes) per sample; 4 samples per block
__global__ __launch_bounds__(256) void front_kernel(
    const float* __restrict__ x, const float* __restrict__ adj,
    const float* __restrict__ lgcn_w, const float* __restrict__ lgcn_b,
    const float* __restrict__ ca1_w1, const float* __restrict__ ca1_w2,
    const float* __restrict__ ca2_w1, const float* __restrict__ ca2_w2,
    const float* __restrict__ meso1_w, const float* __restrict__ meso2_w,
    const int* __restrict__ idx16, const int* __restrict__ idx7,
    f16* __restrict__ catb, float* __restrict__ outp, int B)
{
  __shared__ __align__(16) float adjT[62*65];
  __shared__ __align__(16) float wf_s[4][496];   // [62][8] padded
  __shared__ __align__(16) float h_s[4][496];    // residual, [62][8] padded
  __shared__ __align__(16) float fw_s[4][800];   // up to 78 rows x 10
  __shared__ float sc_s[4][80];
  __shared__ float t_s[4][64];                   // mlp hidden (avg|max)
  __shared__ float small_s[4][16];               // avg[5], mx[5], att1[5]
  __shared__ float v62_s[4][192];                // avg2[62], mx2[62](+64), att2[62](+128)
  __shared__ float mw_s[100];                    // meso1_w | meso2_w

  const int tid = threadIdx.x;
  const int w = tid >> 6;
  const int lane = tid & 63;
  const long b = (long)blockIdx.x * 4 + w;

  for (int t = tid; t < 62*62; t += 256) {
    int i = t / 62, j = t - i*62;
    adjT[j*65 + i] = adj[t];
  }
  if (tid < 50) mw_s[tid] = meso1_w[tid];
  else if (tid < 100) mw_s[tid] = meso2_w[tid - 50];
  __syncthreads();

  const float* xr = x + b * 310;
  if (lane < 62) {
    float wf[5] = {0,0,0,0,0};
    #pragma unroll
    for (int j = 0; j < 5; ++j) {
      float xv = xr[j*62 + lane];
      #pragma unroll
      for (int d = 0; d < 5; ++d) wf[d] += xv * lgcn_w[j*5 + d];
    }
    #pragma unroll
    for (int d = 0; d < 5; ++d) wf_s[w][lane*8 + d] = wf[d];
  }
  __syncthreads();
  if (lane < 62) {
    float acc[5];
    #pragma unroll
    for (int d = 0; d < 5; ++d) acc[d] = lgcn_b[d];
    for (int j = 0; j < 62; ++j) {
      float a = adjT[j*65 + lane];
      float4 w4 = *(const float4*)&wf_s[w][j*8];
      float w5 = wf_s[w][j*8 + 4];
      acc[0] += a*w4.x; acc[1] += a*w4.y; acc[2] += a*w4.z; acc[3] += a*w4.w; acc[4] += a*w5;
    }
    #pragma unroll
    for (int d = 0; d < 5; ++d) h_s[w][lane*8 + d] = acc[d];
  }
  __syncthreads();
  for (int p = lane; p < 310; p += 64) {
    int d = p / 62, i = p - d*62;
    catb[b*736 + p] = (f16)h_s[w][i*8 + d];
  }
  if (lane < 5) {
    float s = 0.f, m = -1e30f;
    for (int i = 0; i < 62; ++i) { float v = h_s[w][i*8 + lane]; s += v; m = fmaxf(m, v); }
    small_s[w][lane] = s * (1.f/62.f);
    small_s[w][5 + lane] = m;
  }
  __syncthreads();
  if (lane < 32) {
    float ta = 0.f, tm = 0.f;
    #pragma unroll
    for (int d = 0; d < 5; ++d) {
      float wv = ca1_w1[lane*5 + d];
      ta += small_s[w][d] * wv;
      tm += small_s[w][5 + d] * wv;
    }
    t_s[w][lane] = fmaxf(ta, 0.f);
    t_s[w][32 + lane] = fmaxf(tm, 0.f);
  }
  __syncthreads();
  if (lane < 5) {
    float sa = 0.f, sm = 0.f;
    for (int o = 0; o < 32; ++o) {
      float wv = ca1_w2[lane*32 + o];
      sa += t_s[w][o] * wv; sm += t_s[w][32 + o] * wv;
    }
    float a = 1.f / (1.f + expf(-(sa + sm)));
    small_s[w][10 + lane] = a;
    outp[(long)B*64 + b*5 + lane] = a;
  }
  __syncthreads();
  if (lane < 62) {
    float s = 0.f, m = -1e30f;
    #pragma unroll
    for (int d = 0; d < 5; ++d) {
      float v = h_s[w][lane*8 + d] * (1.f + small_s[w][10 + d]);
      s += v; m = fmaxf(m, v);
    }
    v62_s[w][lane] = s * (1.f/5.f);
    v62_s[w][64 + lane] = m;
  }
  __syncthreads();
  if (lane < 32) {
    float ta = 0.f, tm = 0.f;
    for (int i = 0; i < 62; ++i) {
      float wv = ca2_w1[lane*62 + i];
      ta += v62_s[w][i] * wv; tm += v62_s[w][64 + i] * wv;
    }
    t_s[w][lane] = fmaxf(ta, 0.f);
    t_s[w][32 + lane] = fmaxf(tm, 0.f);
  }
  __syncthreads();
  if (lane < 62) {
    float sa = 0.f, sm = 0.f;
    for (int o = 0; o < 32; ++o) {
      float wv = ca2_w2[lane*32 + o];
      sa += t_s[w][o] * wv; sm += t_s[w][32 + o] * wv;
    }
    float a = 1.f / (1.f + expf(-(sa + sm)));
    v62_s[w][128 + lane] = a;
    outp[(long)B*69 + b*62 + lane] = a;
  }
  __syncthreads();
  for (int p = lane; p < 310; p += 64) {
    int d = p / 62, i = p - d*62;
    catb[b*736 + 310 + p] = (f16)(h_s[w][i*8 + d] * (1.f + small_s[w][10 + d]) * (1.f + v62_s[w][128 + i]));
  }
  if (lane == 0) catb[b*736 + 735] = (f16)0.f;
  __syncthreads();
  meso_part<4,16,620>(c_g16_st, c_g16_n, lane, b, h_s[w], idx16, mw_s, fw_s[w], sc_s[w], catb);
  __syncthreads();
  meso_part<8,7,700>(c_g7_st, c_g7_n, lane, b, h_s[w], idx7, mw_s + 50, fw_s[w], sc_s[w], catb);
}

// transpose weights to f16 [N][K] (K contiguous), pad w1 K to 736
__global__ void wcvt_kernel(const float* __restrict__ w1, const float* __restrict__ w2,
                            const float* __restrict__ w3,
                            f16* __restrict__ w1T, f16* __restrict__ w2T, f16* __restrict__ w3T)
{
  int i = blockIdx.x * 256 + threadIdx.x;
  if (i < 256*736) {
    int n = i / 736, k = i - n*736;
    w1T[i] = (f16)(k < 735 ? w1[k*256 + n] : 0.f);
    return;
  }
  int j = i - 256*736;
  if (j < 128*256) {
    int n = j >> 8, k = j & 255;
    w2T[j] = (f16)w2[k*128 + n];
    return;
  }
  int q = j - 128*256;
  if (q < 64*128) {
    int n = q >> 7, k = q & 127;
    w3T[q] = (f16)w3[k*64 + n];
  }
}

// fused 3-layer MLP via f16 MFMA; 64 samples/block, 4 waves
__global__ __launch_bounds__(256) void mlp_mfma(
    const f16* __restrict__ cat,
    const f16* __restrict__ w1T, const f16* __restrict__ w2T, const f16* __restrict__ w3T,
    const float* __restrict__ b1, const float* __restrict__ g1, const float* __restrict__ be1,
    const float* __restrict__ m1, const float* __restrict__ v1,
    const float* __restrict__ b2, const float* __restrict__ g2, const float* __restrict__ be2,
    const float* __restrict__ m2, const float* __restrict__ v2,
    const float* __restrict__ b3, const float* __restrict__ g3, const float* __restrict__ be3,
    const float* __restrict__ m3, const float* __restrict__ v3,
    float* __restrict__ outp)
{
  __shared__ __align__(16) f16 a_lds[64*32];    // 4 KB, K-step tile, chunk-swizzled
  __shared__ __align__(16) f16 y1s[64*256];     // 32 KB, swizzled
  __shared__ __align__(16) f16 y2s[64*128];     // 16 KB, swizzled

  const int tid = threadIdx.x;
  const int wv = tid >> 6;
  const int lane = tid & 63;
  const int ln = lane & 15;      // frag row/col within 16
  const int kg = lane >> 4;      // k-group 0..3 (8 elems each)
  const long b0 = (long)blockIdx.x * 64;

  // ---------- layer 1: (64x736)@(736x256), wave wv -> cols wv*64..+63 ----------
  f32x4 zero = {0.f, 0.f, 0.f, 0.f};
  f32x4 acc1[4][4];
  #pragma unroll
  for (int i = 0; i < 4; ++i)
    #pragma unroll
    for (int j = 0; j < 4; ++j) acc1[i][j] = zero;

  // A staging: thread t -> row sr=t>>2, source chunk scs=t&3; LDS slot chunk = scs ^ ((sr>>1)&3)
  const int sr  = tid >> 2;
  const int scs = tid & 3;
  const int sdst = sr*64 + ((scs ^ ((sr >> 1) & 3)) << 4);   // byte offset
  const f16* aSrc = cat + (b0 + sr)*736 + scs*8;

  // A-frag read offsets (swizzled), per row-frag mr
  int aoff[4];
  #pragma unroll
  for (int mr = 0; mr < 4; ++mr) {
    int r = mr*16 + ln;
    aoff[mr] = r*64 + ((kg ^ ((r >> 1) & 3)) << 4);
  }

  // B pointers (w1T [256][736], k contiguous)
  const f16* w1p[4];
  #pragma unroll
  for (int nc = 0; nc < 4; ++nc)
    w1p[nc] = w1T + (size_t)(wv*64 + nc*16 + ln)*736 + kg*8;

  f16x8 bF[4], bN[4];
  #pragma unroll
  for (int nc = 0; nc < 4; ++nc) bF[nc] = *(const f16x8*)(w1p[nc]);
  f16x8 aReg = *(const f16x8*)(aSrc);
  f16x8 aRegN;

  for (int s = 0; s < 23; ++s) {
    __syncthreads();
    *(f16x8*)((char*)a_lds + sdst) = aReg;
    __syncthreads();
    if (s < 22) {
      aRegN = *(const f16x8*)(aSrc + (s + 1)*32);
      #pragma unroll
      for (int nc = 0; nc < 4; ++nc) bN[nc] = *(const f16x8*)(w1p[nc] + (s + 1)*32);
    }
    #pragma unroll
    for (int mr = 0; mr < 4; ++mr) {
      f16x8 af = *(const f16x8*)((const char*)a_lds + aoff[mr]);
      #pragma unroll
      for (int nc = 0; nc < 4; ++nc)
        acc1[mr][nc] = __builtin_amdgcn_mfma_f32_16x16x32_f16(af, bF[nc], acc1[mr][nc], 0, 0, 0);
    }
    aReg = aRegN;
    #pragma unroll
    for (int nc = 0; nc < 4; ++nc) bF[nc] = bN[nc];
  }

  // epilogue 1: BN + lrelu -> y1s (f16, swizzled). D: row = mr*16 + 4*kg + ri, col = nc*16+ln (+wv*64)
  #pragma unroll
  for (int nc = 0; nc < 4; ++nc) {
    int n = wv*64 + nc*16 + ln;
    float sc = g1[n] * rsqrtf(v1[n] + BN_EPS);
    float bm = b1[n] - m1[n];
    float bo = be1[n];
    int c = n >> 3;
    #pragma unroll
    for (int mr = 0; mr < 4; ++mr) {
      #pragma unroll
      for (int ri = 0; ri < 4; ++ri) {
        int r = mr*16 + kg*4 + ri;
        float y = lrelu((acc1[mr][nc][ri] + bm)*sc + bo);
        int off = r*512 + ((c ^ (r & 7)) << 4) + ((n & 7) << 1);
        *(f16*)((char*)y1s + off) = (f16)y;
      }
    }
  }
  __syncthreads();

  // ---------- layer 2: (64x256)@(256x128), wave wv -> cols wv*32..+31 ----------
  f32x4 acc2[4][2];
  #pragma unroll
  for (int i = 0; i < 4; ++i) { acc2[i][0] = zero; acc2[i][1] = zero; }
  const f16* w2p[2];
  #pragma unroll
  for (int nc = 0; nc < 2; ++nc)
    w2p[nc] = w2T + (size_t)(wv*32 + nc*16 + ln)*256 + kg*8;

  #pragma unroll
  for (int s2 = 0; s2 < 8; ++s2) {
    f16x8 b2f[2];
    #pragma unroll
    for (int nc = 0; nc < 2; ++nc) b2f[nc] = *(const f16x8*)(w2p[nc] + s2*32);
    #pragma unroll
    for (int mr = 0; mr < 4; ++mr) {
      int r = mr*16 + ln;
      int c = s2*4 + kg;
      f16x8 af = *(const f16x8*)((const char*)y1s + r*512 + ((c ^ (r & 7)) << 4));
      #pragma unroll
      for (int nc = 0; nc < 2; ++nc)
        acc2[mr][nc] = __builtin_amdgcn_mfma_f32_16x16x32_f16(af, b2f[nc], acc2[mr][nc], 0, 0, 0);
    }
  }
  #pragma unroll
  for (int nc = 0; nc < 2; ++nc) {
    int n = wv*32 + nc*16 + ln;
    float sc = g2[n] * rsqrtf(v2[n] + BN_EPS);
    float bm = b2[n] - m2[n];
    float bo = be2[n];
    int c = n >> 3;
    #pragma unroll
    for (int mr = 0; mr < 4; ++mr) {
      #pragma unroll
      for (int ri = 0; ri < 4; ++ri) {
        int r = mr*16 + kg*4 + ri;
        float y = lrelu((acc2[mr][nc][ri] + bm)*sc + bo);
        int off = r*256 + ((c ^ (r & 7)) << 4) + ((n & 7) << 1);
        *(f16*)((char*)y2s + off) = (f16)y;
      }
    }
  }
  __syncthreads();

  // ---------- layer 3: (64x128)@(128x64), wave wv -> cols wv*16..+15 ----------
  f32x4 acc3[4];
  #pragma unroll
  for (int i = 0; i < 4; ++i) acc3[i] = zero;
  const f16* w3p = w3T + (size_t)(wv*16 + ln)*128 + kg*8;

  #pragma unroll
  for (int s3 = 0; s3 < 4; ++s3) {
    f16x8 bf = *(const f16x8*)(w3p + s3*32);
    #pragma unroll
    for (int mr = 0; mr < 4; ++mr) {
      int r = mr*16 + ln;
      int c = s3*4 + kg;
      f16x8 af = *(const f16x8*)((const char*)y2s + r*256 + ((c ^ (r & 7)) << 4));
      acc3[mr] = __builtin_amdgcn_mfma_f32_16x16x32_f16(af, bf, acc3[mr], 0, 0, 0);
    }
  }
  {
    int n = wv*16 + ln;
    float sc = g3[n] * rsqrtf(v3[n] + BN_EPS);
    float bm = b3[n] - m3[n];
    float bo = be3[n];
    #pragma unroll
    for (int mr = 0; mr < 4; ++mr) {
      #pragma unroll
      for (int ri = 0; ri < 4; ++ri) {
        int r = mr*16 + kg*4 + ri;
        float y = lrelu((acc3[mr][ri] + bm)*sc + bo);
        outp[(size_t)(b0 + r)*64 + n] = y;
      }
    }
  }
}

extern "C" void kernel_launch(void* const* d_in, const int* in_sizes, int n_in,
                              void* d_out, int out_size, void* d_ws, size_t ws_size,
                              hipStream_t stream) {
  const float* x       = (const float*)d_in[0];
  const float* adj     = (const float*)d_in[1];
  const float* lgcn_w  = (const float*)d_in[2];
  const float* lgcn_b  = (const float*)d_in[3];
  const float* ca1_w1  = (const float*)d_in[4];
  const float* ca1_w2  = (const float*)d_in[5];
  const float* ca2_w1  = (const float*)d_in[6];
  const float* ca2_w2  = (const float*)d_in[7];
  const float* meso1_w = (const float*)d_in[8];
  const float* meso2_w = (const float*)d_in[9];
  const int*   idx16   = (const int*)d_in[10];
  const int*   idx7    = (const int*)d_in[11];
  const float* w1 = (const float*)d_in[12];
  const float* b1 = (const float*)d_in[13];
  const float* w2 = (const float*)d_in[14];
  const float* b2 = (const float*)d_in[15];
  const float* w3 = (const float*)d_in[16];
  const float* b3 = (const float*)d_in[17];
  const float* g1 = (const float*)d_in[18];
  const float* be1= (const float*)d_in[19];
  const float* m1 = (const float*)d_in[20];
  const float* v1 = (const float*)d_in[21];
  const float* g2 = (const float*)d_in[22];
  const float* be2= (const float*)d_in[23];
  const float* m2 = (const float*)d_in[24];
  const float* v2 = (const float*)d_in[25];
  const float* g3 = (const float*)d_in[26];
  const float* be3= (const float*)d_in[27];
  const float* m3 = (const float*)d_in[28];
  const float* v3 = (const float*)d_in[29];

  const int B = in_sizes[0] / 310;

  // ws layout (bytes): cat f16 [B][736] | w1T f16 [256][736] | w2T f16 [128][256] | w3T f16 [64][128]
  const size_t catBytes = (size_t)B * 736 * sizeof(f16);
  char* wsc = (char*)d_ws;
  f16* catb = (f16*)wsc;
  f16* w1T  = (f16*)(wsc + catBytes);
  f16* w2T  = (f16*)(wsc + catBytes + 256*736*sizeof(f16));
  f16* w3T  = (f16*)(wsc + catBytes + (256*736 + 128*256)*sizeof(f16));
  const size_t need = catBytes + (256*736 + 128*256 + 64*128)*sizeof(f16);
  if (ws_size < need) return;  // fail visibly

  wcvt_kernel<<<(256*736 + 128*256 + 64*128 + 255)/256, 256, 0, stream>>>(w1, w2, w3, w1T, w2T, w3T);
  front_kernel<<<B/4, 256, 0, stream>>>(x, adj, lgcn_w, lgcn_b, ca1_w1, ca1_w2,
                                        ca2_w1, ca2_w2, meso1_w, meso2_w,
                                        idx16, idx7, catb, (float*)d_out, B);
  mlp_mfma<<<B/64, 256, 0, stream>>>(catb, w1T, w2T, w3T,
                                     b1, g1, be1, m1, v1,
                                     b2, g2, be2, m2, v2,
                                     b3, g3, be3, m3, v3, (float*)d_out);
}

// Round 4
// 640.740 us; speedup vs baseline: 1.9036x; 1.0956x over previous
//
#include <hip/hip_runtime.h>
#include <math.h>

#define BN_EPS 1e-5f
#define SLOPE 0.01f

typedef _Float16 f16;
typedef _Float16 f16x8 __attribute__((ext_vector_type(8)));
typedef float f32x4 __attribute__((ext_vector_type(4)));

__device__ __constant__ int c_g16_st[16] = {0,5,8,11,14,17,20,25,30,35,46,49,52,55,58,61};
__device__ __constant__ int c_g16_n[16]  = {5,3,3,3,3,3,5,5,5,11,3,3,3,3,3,12};
__device__ __constant__ int c_g7_st[7]   = {0,5,14,23,48,57,66};
__device__ __constant__ int c_g7_n[7]    = {5,9,9,25,9,9,12};

__device__ __forceinline__ float lrelu(float y) { return y > 0.f ? y : SLOPE * y; }

// meso helper: G teams of T lanes each, group k -> cat[b*736 + BASE + g*G + k]
template<int T, int G, int BASE>
__device__ void meso_part(const int* __restrict__ st_arr, const int* __restrict__ n_arr,
                          int lane, long b, const float* h, const int* __restrict__ idxa,
                          const float* mw, float* fwbuf, float* scbuf,
                          f16* __restrict__ catb)
{
  const int team = lane / T, slot = lane - team * T;
  int st = 0, n = 0;
  if (team < G) { st = st_arr[team]; n = n_arr[team]; }
  float sp[10] = {0,0,0,0,0,0,0,0,0,0};
  if (team < G) {
    for (int j = slot; j < n; j += T) {
      int ri = idxa[st + j];
      float sv[5];
      #pragma unroll
      for (int g = 0; g < 5; ++g) sv[g] = h[ri*8 + g];
      #pragma unroll
      for (int t = 0; t < 10; ++t) {
        float f = sv[0]*mw[t] + sv[1]*mw[10+t] + sv[2]*mw[20+t] + sv[3]*mw[30+t] + sv[4]*mw[40+t];
        fwbuf[(st+j)*10 + t] = f;
        sp[t] += f;
      }
    }
  }
  #pragma unroll
  for (int off = 1; off < T; off <<= 1) {
    #pragma unroll
    for (int t = 0; t < 10; ++t) sp[t] += __shfl_xor(sp[t], off);
  }
  __syncthreads();
  if (team < G) {
    for (int j = slot; j < n; j += T) {
      float sc = 0.f;
      #pragma unroll
      for (int t = 0; t < 10; ++t) sc += fwbuf[(st+j)*10 + t] * sp[t];
      scbuf[st + j] = sc;
    }
  }
  __syncthreads();
  float po[5] = {0,0,0,0,0};
  if (team < G) {
    float mx = -1e30f;
    for (int jj = 0; jj < n; ++jj) mx = fmaxf(mx, scbuf[st + jj]);
    float sum = 0.f;
    for (int jj = 0; jj < n; ++jj) sum += expf(scbuf[st + jj] - mx);
    float inv = 1.f / sum;
    for (int j = slot; j < n; j += T) {
      float a = expf(scbuf[st + j] - mx) * inv;
      int ri = idxa[st + j];
      #pragma unroll
      for (int g = 0; g < 5; ++g) po[g] += a * h[ri*8 + g];
    }
  }
  #pragma unroll
  for (int off = 1; off < T; off <<= 1) {
    #pragma unroll
    for (int g = 0; g < 5; ++g) po[g] += __shfl_xor(po[g], off);
  }
  if (team < G && slot == 0) {
    #pragma unroll
    for (int g = 0; g < 5; ++g) catb[b*736 + BASE + g*G + team] = (f16)po[g];
  }
}

// prep: transpose weights to f16 [N][K] + build Mp[320][320] f16 (cols = d*62+i, k = g*62+j)
__global__ void wcvt_kernel(const float* __restrict__ w1, const float* __restrict__ w2,
                            const float* __restrict__ w3,
                            const float* __restrict__ adj, const float* __restrict__ lgcn_w,
                            f16* __restrict__ w1T, f16* __restrict__ w2T, f16* __restrict__ w3T,
                            f16* __restrict__ Mp)
{
  int i = blockIdx.x * 256 + threadIdx.x;
  if (i < 256*736) {
    int n = i / 736, k = i - n*736;
    w1T[i] = (f16)(k < 735 ? w1[k*256 + n] : 0.f);
    return;
  }
  int j = i - 256*736;
  if (j < 128*256) {
    int n = j >> 8, k = j & 255;
    w2T[j] = (f16)w2[k*128 + n];
    return;
  }
  int q = j - 128*256;
  if (q < 64*128) {
    int n = q >> 7, k = q & 127;
    w3T[q] = (f16)w3[k*64 + n];
    return;
  }
  int m = q - 64*128;
  if (m < 320*320) {
    int col = m / 320, k = m - col*320;
    float v = 0.f;
    if (col < 310 && k < 310) {
      int d = col / 62, ii = col - d*62;
      int g = k / 62,  jj = k - g*62;
      v = adj[ii*62 + jj] * lgcn_w[g*5 + d];
    }
    Mp[m] = (f16)v;
  }
}

// lgcn as GEMM: cat[b, 0:310] = x[b,:] @ Mp + lgcn_b   (64 samples/block, 4 waves)
__global__ __launch_bounds__(256) void gemm_h(
    const float* __restrict__ x, const f16* __restrict__ Mp,
    const float* __restrict__ lgcn_b, f16* __restrict__ catb)
{
  __shared__ __align__(16) f16 a_lds[64*320];   // 40 KB, chunk-swizzled; reused for D

  const int tid = threadIdx.x;
  const int wv = tid >> 6;
  const int lane = tid & 63;
  const int ln = lane & 15;
  const int kg = lane >> 4;
  const long b0 = (long)blockIdx.x * 64;

  // B pointers + first-step prefetch (Mp is L2-resident, 200 KB)
  const f16* mp[5];
  #pragma unroll
  for (int nc = 0; nc < 5; ++nc)
    mp[nc] = Mp + (size_t)(wv*80 + nc*16 + ln)*320 + kg*8;
  f16x8 bF[5], bN[5];
  #pragma unroll
  for (int nc = 0; nc < 5; ++nc) bF[nc] = *(const f16x8*)(mp[nc]);

  // stage A (rows wv*16..+15): zero k-pad chunks 38,39, then f32->f16 float2 loads
  for (int rr = 0; rr < 16; ++rr) {
    int row = wv*16 + rr;
    if (lane < 8) {
      int c = 38 + (lane >> 2);
      *(unsigned*)((char*)a_lds + row*640 + ((c ^ (row & 7)) << 4) + (lane & 3)*4) = 0u;
    }
    const float* xr = x + (b0 + row)*310;
    for (int f = lane; f < 155; f += 64) {
      float2 v = *(const float2*)(xr + 2*f);
      int k = 2*f;
      int c = k >> 3;
      f16 h0 = (f16)v.x, h1 = (f16)v.y;
      unsigned u = (unsigned)*(unsigned short*)&h0 | ((unsigned)*(unsigned short*)&h1 << 16);
      *(unsigned*)((char*)a_lds + row*640 + ((c ^ (row & 7)) << 4) + (k & 7)*2) = u;
    }
  }
  __syncthreads();

  f32x4 zero = {0.f, 0.f, 0.f, 0.f};
  f32x4 acc[4][5];
  #pragma unroll
  for (int mr = 0; mr < 4; ++mr)
    #pragma unroll
    for (int nc = 0; nc < 5; ++nc) acc[mr][nc] = zero;

  for (int s = 0; s < 10; ++s) {
    if (s < 9) {
      #pragma unroll
      for (int nc = 0; nc < 5; ++nc) bN[nc] = *(const f16x8*)(mp[nc] + (s + 1)*32);
    }
    #pragma unroll
    for (int mr = 0; mr < 4; ++mr) {
      int r = mr*16 + ln;
      int c = s*4 + kg;
      f16x8 af = *(const f16x8*)((const char*)a_lds + r*640 + ((c ^ (r & 7)) << 4));
      #pragma unroll
      for (int nc = 0; nc < 5; ++nc)
        acc[mr][nc] = __builtin_amdgcn_mfma_f32_16x16x32_f16(af, bF[nc], acc[mr][nc], 0, 0, 0);
    }
    #pragma unroll
    for (int nc = 0; nc < 5; ++nc) bF[nc] = bN[nc];
  }

  // D -> LDS (f16, swizzled), then coalesced row writes of cat[b][0:312)
  __syncthreads();
  #pragma unroll
  for (int nc = 0; nc < 5; ++nc) {
    int n = wv*80 + nc*16 + ln;
    float bias = (n < 310) ? lgcn_b[n / 62] : 0.f;
    int c = n >> 3;
    #pragma unroll
    for (int mr = 0; mr < 4; ++mr) {
      #pragma unroll
      for (int ri = 0; ri < 4; ++ri) {
        int r = mr*16 + kg*4 + ri;
        f16 val = (f16)(acc[mr][nc][ri] + bias);
        *(f16*)((char*)a_lds + r*640 + ((c ^ (r & 7)) << 4) + (n & 7)*2) = val;
      }
    }
  }
  __syncthreads();
  for (int rr = 0; rr < 16; ++rr) {
    int row = wv*16 + rr;
    if (lane < 39) {
      int c = lane;
      f16x8 v = *(const f16x8*)((const char*)a_lds + row*640 + ((c ^ (row & 7)) << 4));
      *(f16x8*)(catb + (b0 + row)*736 + c*8) = v;
    }
  }
}

// per-sample front work (post-lgcn); one wave per sample, 4 samples/block
__global__ __launch_bounds__(256) void front2(
    const float* __restrict__ ca1_w1, const float* __restrict__ ca1_w2,
    const float* __restrict__ ca2_w1, const float* __restrict__ ca2_w2,
    const float* __restrict__ meso1_w, const float* __restrict__ meso2_w,
    const int* __restrict__ idx16, const int* __restrict__ idx7,
    f16* __restrict__ catb, float* __restrict__ outp, int B)
{
  __shared__ __align__(16) float h_s[4][496];   // [62][8] padded
  __shared__ __align__(16) float fw_s[4][800];
  __shared__ float sc_s[4][80];
  __shared__ float t_s[4][64];
  __shared__ float small_s[4][16];
  __shared__ float v62_s[4][192];
  __shared__ float mw_s[100];

  const int tid = threadIdx.x;
  const int w = tid >> 6;
  const int lane = tid & 63;
  const long b = (long)blockIdx.x * 4 + w;

  if (tid < 50) mw_s[tid] = meso1_w[tid];
  else if (tid < 100) mw_s[tid] = meso2_w[tid - 50];

  // load h from cat[0:310] (layout p = d*62+i -> h_s[i*8+d])
  for (int p = lane; p < 310; p += 64) {
    float v = (float)catb[b*736 + p];
    int d = p / 62, i = p - d*62;
    h_s[w][i*8 + d] = v;
  }
  __syncthreads();

  // CA1 stats: 40 lanes (d*8+q), 8-chunk per lane, shfl-reduce over 8
  {
    int d = lane >> 3, q = lane & 7;
    float s = 0.f, m = -1e30f;
    if (d < 5) {
      #pragma unroll
      for (int e = 0; e < 8; ++e) {
        int i = q*8 + e;
        if (i < 62) { float v = h_s[w][i*8 + d]; s += v; m = fmaxf(m, v); }
      }
    }
    #pragma unroll
    for (int off = 1; off < 8; off <<= 1) {
      s += __shfl_xor(s, off);
      m = fmaxf(m, __shfl_xor(m, off));
    }
    if (d < 5 && q == 0) {
      small_s[w][d] = s * (1.f/62.f);
      small_s[w][5 + d] = m;
    }
  }
  __syncthreads();
  // CA1 mlp hidden
  if (lane < 32) {
    float ta = 0.f, tm = 0.f;
    #pragma unroll
    for (int d = 0; d < 5; ++d) {
      float wv = ca1_w1[lane*5 + d];
      ta += small_s[w][d] * wv;
      tm += small_s[w][5 + d] * wv;
    }
    t_s[w][lane] = fmaxf(ta, 0.f);
    t_s[w][32 + lane] = fmaxf(tm, 0.f);
  }
  __syncthreads();
  // att1
  if (lane < 5) {
    float sa = 0.f, sm = 0.f;
    for (int o = 0; o < 32; ++o) {
      float wv = ca1_w2[lane*32 + o];
      sa += t_s[w][o] * wv; sm += t_s[w][32 + o] * wv;
    }
    float a = 1.f / (1.f + expf(-(sa + sm)));
    small_s[w][10 + lane] = a;
    outp[(long)B*64 + b*5 + lane] = a;
  }
  __syncthreads();
  // CA2 stats (per i over d)
  if (lane < 62) {
    float s = 0.f, m = -1e30f;
    #pragma unroll
    for (int d = 0; d < 5; ++d) {
      float v = h_s[w][lane*8 + d] * (1.f + small_s[w][10 + d]);
      s += v; m = fmaxf(m, v);
    }
    v62_s[w][lane] = s * (1.f/5.f);
    v62_s[w][64 + lane] = m;
  }
  __syncthreads();
  // CA2 mlp hidden: 64 lanes (half avg, half max)
  {
    int half = lane >> 5;
    int o = lane & 31;
    const float* src = &v62_s[w][half*64];
    float t = 0.f;
    for (int i = 0; i < 62; ++i) t += src[i] * ca2_w1[o*62 + i];
    t_s[w][half*32 + o] = fmaxf(t, 0.f);
  }
  __syncthreads();
  // att2
  if (lane < 62) {
    float sa = 0.f, sm = 0.f;
    for (int o = 0; o < 32; ++o) {
      float wv = ca2_w2[lane*32 + o];
      sa += t_s[w][o] * wv; sm += t_s[w][32 + o] * wv;
    }
    float a = 1.f / (1.f + expf(-(sa + sm)));
    v62_s[w][128 + lane] = a;
    outp[(long)B*69 + b*62 + lane] = a;
  }
  __syncthreads();
  // out_flat part of cat
  for (int p = lane; p < 310; p += 64) {
    int d = p / 62, i = p - d*62;
    catb[b*736 + 310 + p] = (f16)(h_s[w][i*8 + d] * (1.f + small_s[w][10 + d]) * (1.f + v62_s[w][128 + i]));
  }
  if (lane == 0) catb[b*736 + 735] = (f16)0.f;
  __syncthreads();
  meso_part<4,16,620>(c_g16_st, c_g16_n, lane, b, h_s[w], idx16, mw_s, fw_s[w], sc_s[w], catb);
  __syncthreads();
  meso_part<8,7,700>(c_g7_st, c_g7_n, lane, b, h_s[w], idx7, mw_s + 50, fw_s[w], sc_s[w], catb);
}

// fused 3-layer MLP via f16 MFMA; 64 samples/block, 4 waves
__global__ __launch_bounds__(256) void mlp_mfma(
    const f16* __restrict__ cat,
    const f16* __restrict__ w1T, const f16* __restrict__ w2T, const f16* __restrict__ w3T,
    const float* __restrict__ b1, const float* __restrict__ g1, const float* __restrict__ be1,
    const float* __restrict__ m1, const float* __restrict__ v1,
    const float* __restrict__ b2, const float* __restrict__ g2, const float* __restrict__ be2,
    const float* __restrict__ m2, const float* __restrict__ v2,
    const float* __restrict__ b3, const float* __restrict__ g3, const float* __restrict__ be3,
    const float* __restrict__ m3, const float* __restrict__ v3,
    float* __restrict__ outp)
{
  __shared__ __align__(16) f16 a_lds[64*32];    // 4 KB, K-step tile, chunk-swizzled
  __shared__ __align__(16) f16 y1s[64*256];     // 32 KB, swizzled
  __shared__ __align__(16) f16 y2s[64*128];     // 16 KB, swizzled

  const int tid = threadIdx.x;
  const int wv = tid >> 6;
  const int lane = tid & 63;
  const int ln = lane & 15;      // frag row/col within 16
  const int kg = lane >> 4;      // k-group 0..3 (8 elems each)
  const long b0 = (long)blockIdx.x * 64;

  // ---------- layer 1: (64x736)@(736x256), wave wv -> cols wv*64..+63 ----------
  f32x4 zero = {0.f, 0.f, 0.f, 0.f};
  f32x4 acc1[4][4];
  #pragma unroll
  for (int i = 0; i < 4; ++i)
    #pragma unroll
    for (int j = 0; j < 4; ++j) acc1[i][j] = zero;

  const int sr  = tid >> 2;
  const int scs = tid & 3;
  const int sdst = sr*64 + ((scs ^ ((sr >> 1) & 3)) << 4);
  const f16* aSrc = cat + (b0 + sr)*736 + scs*8;

  int aoff[4];
  #pragma unroll
  for (int mr = 0; mr < 4; ++mr) {
    int r = mr*16 + ln;
    aoff[mr] = r*64 + ((kg ^ ((r >> 1) & 3)) << 4);
  }

  const f16* w1p[4];
  #pragma unroll
  for (int nc = 0; nc < 4; ++nc)
    w1p[nc] = w1T + (size_t)(wv*64 + nc*16 + ln)*736 + kg*8;

  f16x8 bF[4], bN[4];
  #pragma unroll
  for (int nc = 0; nc < 4; ++nc) bF[nc] = *(const f16x8*)(w1p[nc]);
  f16x8 aReg = *(const f16x8*)(aSrc);
  f16x8 aRegN;

  for (int s = 0; s < 23; ++s) {
    __syncthreads();
    *(f16x8*)((char*)a_lds + sdst) = aReg;
    __syncthreads();
    if (s < 22) {
      aRegN = *(const f16x8*)(aSrc + (s + 1)*32);
      #pragma unroll
      for (int nc = 0; nc < 4; ++nc) bN[nc] = *(const f16x8*)(w1p[nc] + (s + 1)*32);
    }
    #pragma unroll
    for (int mr = 0; mr < 4; ++mr) {
      f16x8 af = *(const f16x8*)((const char*)a_lds + aoff[mr]);
      #pragma unroll
      for (int nc = 0; nc < 4; ++nc)
        acc1[mr][nc] = __builtin_amdgcn_mfma_f32_16x16x32_f16(af, bF[nc], acc1[mr][nc], 0, 0, 0);
    }
    aReg = aRegN;
    #pragma unroll
    for (int nc = 0; nc < 4; ++nc) bF[nc] = bN[nc];
  }

  // epilogue 1: BN + lrelu -> y1s (f16, swizzled)
  #pragma unroll
  for (int nc = 0; nc < 4; ++nc) {
    int n = wv*64 + nc*16 + ln;
    float sc = g1[n] * rsqrtf(v1[n] + BN_EPS);
    float bm = b1[n] - m1[n];
    float bo = be1[n];
    int c = n >> 3;
    #pragma unroll
    for (int mr = 0; mr < 4; ++mr) {
      #pragma unroll
      for (int ri = 0; ri < 4; ++ri) {
        int r = mr*16 + kg*4 + ri;
        float y = lrelu((acc1[mr][nc][ri] + bm)*sc + bo);
        int off = r*512 + ((c ^ (r & 7)) << 4) + ((n & 7) << 1);
        *(f16*)((char*)y1s + off) = (f16)y;
      }
    }
  }
  __syncthreads();

  // ---------- layer 2: (64x256)@(256x128), wave wv -> cols wv*32..+31 ----------
  f32x4 acc2[4][2];
  #pragma unroll
  for (int i = 0; i < 4; ++i) { acc2[i][0] = zero; acc2[i][1] = zero; }
  const f16* w2p[2];
  #pragma unroll
  for (int nc = 0; nc < 2; ++nc)
    w2p[nc] = w2T + (size_t)(wv*32 + nc*16 + ln)*256 + kg*8;

  #pragma unroll
  for (int s2 = 0; s2 < 8; ++s2) {
    f16x8 b2f[2];
    #pragma unroll
    for (int nc = 0; nc < 2; ++nc) b2f[nc] = *(const f16x8*)(w2p[nc] + s2*32);
    #pragma unroll
    for (int mr = 0; mr < 4; ++mr) {
      int r = mr*16 + ln;
      int c = s2*4 + kg;
      f16x8 af = *(const f16x8*)((const char*)y1s + r*512 + ((c ^ (r & 7)) << 4));
      #pragma unroll
      for (int nc = 0; nc < 2; ++nc)
        acc2[mr][nc] = __builtin_amdgcn_mfma_f32_16x16x32_f16(af, b2f[nc], acc2[mr][nc], 0, 0, 0);
    }
  }
  #pragma unroll
  for (int nc = 0; nc < 2; ++nc) {
    int n = wv*32 + nc*16 + ln;
    float sc = g2[n] * rsqrtf(v2[n] + BN_EPS);
    float bm = b2[n] - m2[n];
    float bo = be2[n];
    int c = n >> 3;
    #pragma unroll
    for (int mr = 0; mr < 4; ++mr) {
      #pragma unroll
      for (int ri = 0; ri < 4; ++ri) {
        int r = mr*16 + kg*4 + ri;
        float y = lrelu((acc2[mr][nc][ri] + bm)*sc + bo);
        int off = r*256 + ((c ^ (r & 7)) << 4) + ((n & 7) << 1);
        *(f16*)((char*)y2s + off) = (f16)y;
      }
    }
  }
  __syncthreads();

  // ---------- layer 3: (64x128)@(128x64), wave wv -> cols wv*16..+15 ----------
  f32x4 acc3[4];
  #pragma unroll
  for (int i = 0; i < 4; ++i) acc3[i] = zero;
  const f16* w3p = w3T + (size_t)(wv*16 + ln)*128 + kg*8;

  #pragma unroll
  for (int s3 = 0; s3 < 4; ++s3) {
    f16x8 bf = *(const f16x8*)(w3p + s3*32);
    #pragma unroll
    for (int mr = 0; mr < 4; ++mr) {
      int r = mr*16 + ln;
      int c = s3*4 + kg;
      f16x8 af = *(const f16x8*)((const char*)y2s + r*256 + ((c ^ (r & 7)) << 4));
      acc3[mr] = __builtin_amdgcn_mfma_f32_16x16x32_f16(af, bf, acc3[mr], 0, 0, 0);
    }
  }
  {
    int n = wv*16 + ln;
    float sc = g3[n] * rsqrtf(v3[n] + BN_EPS);
    float bm = b3[n] - m3[n];
    float bo = be3[n];
    #pragma unroll
    for (int mr = 0; mr < 4; ++mr) {
      #pragma unroll
      for (int ri = 0; ri < 4; ++ri) {
        int r = mr*16 + kg*4 + ri;
        float y = lrelu((acc3[mr][ri] + bm)*sc + bo);
        outp[(size_t)(b0 + r)*64 + n] = y;
      }
    }
  }
}

extern "C" void kernel_launch(void* const* d_in, const int* in_sizes, int n_in,
                              void* d_out, int out_size, void* d_ws, size_t ws_size,
                              hipStream_t stream) {
  const float* x       = (const float*)d_in[0];
  const float* adj     = (const float*)d_in[1];
  const float* lgcn_w  = (const float*)d_in[2];
  const float* lgcn_b  = (const float*)d_in[3];
  const float* ca1_w1  = (const float*)d_in[4];
  const float* ca1_w2  = (const float*)d_in[5];
  const float* ca2_w1  = (const float*)d_in[6];
  const float* ca2_w2  = (const float*)d_in[7];
  const float* meso1_w = (const float*)d_in[8];
  const float* meso2_w = (const float*)d_in[9];
  const int*   idx16   = (const int*)d_in[10];
  const int*   idx7    = (const int*)d_in[11];
  const float* w1 = (const float*)d_in[12];
  const float* b1 = (const float*)d_in[13];
  const float* w2 = (const float*)d_in[14];
  const float* b2 = (const float*)d_in[15];
  const float* w3 = (const float*)d_in[16];
  const float* b3 = (const float*)d_in[17];
  const float* g1 = (const float*)d_in[18];
  const float* be1= (const float*)d_in[19];
  const float* m1 = (const float*)d_in[20];
  const float* v1 = (const float*)d_in[21];
  const float* g2 = (const float*)d_in[22];
  const float* be2= (const float*)d_in[23];
  const float* m2 = (const float*)d_in[24];
  const float* v2 = (const float*)d_in[25];
  const float* g3 = (const float*)d_in[26];
  const float* be3= (const float*)d_in[27];
  const float* m3 = (const float*)d_in[28];
  const float* v3 = (const float*)d_in[29];

  const int B = in_sizes[0] / 310;

  // ws: cat f16 [B][736] | w1T [256][736] | w2T [128][256] | w3T [64][128] | Mp [320][320]
  const size_t catBytes = (size_t)B * 736 * sizeof(f16);
  char* wsc = (char*)d_ws;
  f16* catb = (f16*)wsc;
  f16* w1T  = (f16*)(wsc + catBytes);
  f16* w2T  = (f16*)(wsc + catBytes + 256*736*sizeof(f16));
  f16* w3T  = (f16*)(wsc + catBytes + (256*736 + 128*256)*sizeof(f16));
  f16* Mp   = (f16*)(wsc + catBytes + (256*736 + 128*256 + 64*128)*sizeof(f16));
  const size_t need = catBytes + (256*736 + 128*256 + 64*128 + 320*320)*sizeof(f16);
  if (ws_size < need) return;  // fail visibly

  const int prepElems = 256*736 + 128*256 + 64*128 + 320*320;
  wcvt_kernel<<<(prepElems + 255)/256, 256, 0, stream>>>(w1, w2, w3, adj, lgcn_w,
                                                         w1T, w2T, w3T, Mp);
  gemm_h<<<B/64, 256, 0, stream>>>(x, Mp, lgcn_b, catb);
  front2<<<B/4, 256, 0, stream>>>(ca1_w1, ca1_w2, ca2_w1, ca2_w2, meso1_w, meso2_w,
                                  idx16, idx7, catb, (float*)d_out, B);
  mlp_mfma<<<B/64, 256, 0, stream>>>(catb, w1T, w2T, w3T,
                                     b1, g1, be1, m1, v1,
                                     b2, g2, be2, m2, v2,
                                     b3, g3, be3, m3, v3, (float*)d_out);
}

// Round 5
// 575.873 us; speedup vs baseline: 2.1180x; 1.1126x over previous
//
#include <hip/hip_runtime.h>
#include <math.h>

#define BN_EPS 1e-5f
#define SLOPE 0.01f

// wave-local barrier: waits own LDS ops + stops compiler reordering.
// Valid because each sample's state is touched by exactly one (lockstep) wave.
#define WSYNC() asm volatile("s_waitcnt lgkmcnt(0)" ::: "memory")

typedef _Float16 f16;
typedef _Float16 f16x8 __attribute__((ext_vector_type(8)));
typedef float f32x4 __attribute__((ext_vector_type(4)));

__device__ __constant__ int c_g16_st[16] = {0,5,8,11,14,17,20,25,30,35,46,49,52,55,58,61};
__device__ __constant__ int c_g16_n[16]  = {5,3,3,3,3,3,5,5,5,11,3,3,3,3,3,12};
__device__ __constant__ int c_g7_st[7]   = {0,5,14,23,48,57,66};
__device__ __constant__ int c_g7_n[7]    = {5,9,9,25,9,9,12};

__device__ __forceinline__ float lrelu(float y) { return y > 0.f ? y : SLOPE * y; }

// register-resident meso: score_j = sv_j . qs, qs_g = sum_t mw[g][t]*sp[t]
// T lanes/team, G teams, R = ceil(max_n/T), group k -> cat[b*736 + BASE + g*G + team]
template<int T, int G, int R, int BASE>
__device__ void meso_reg(const int* __restrict__ st_arr, const int* __restrict__ n_arr,
                         int lane, long b, const float* h, const int* idx_s,
                         const float* mw, float* scb, f16* __restrict__ catb)
{
  const int team = lane / T, slot = lane - team * T;
  int st = 0, n = 0;
  if (team < G) { st = st_arr[team]; n = n_arr[team]; }

  float sv[R][5];
  bool act[R];
  float sp[10] = {0,0,0,0,0,0,0,0,0,0};
  #pragma unroll
  for (int rr = 0; rr < R; ++rr) {
    int j = slot + rr*T;
    act[rr] = (team < G) && (j < n);
    #pragma unroll
    for (int g = 0; g < 5; ++g) sv[rr][g] = 0.f;
    if (act[rr]) {
      int ri = idx_s[st + j];
      #pragma unroll
      for (int g = 0; g < 5; ++g) sv[rr][g] = h[ri*9 + g];
      #pragma unroll
      for (int t = 0; t < 10; ++t)
        sp[t] += sv[rr][0]*mw[t] + sv[rr][1]*mw[10+t] + sv[rr][2]*mw[20+t]
               + sv[rr][3]*mw[30+t] + sv[rr][4]*mw[40+t];
    }
  }
  #pragma unroll
  for (int off = 1; off < T; off <<= 1)
    #pragma unroll
    for (int t = 0; t < 10; ++t) sp[t] += __shfl_xor(sp[t], off);

  float qs[5];
  #pragma unroll
  for (int g = 0; g < 5; ++g) {
    float q = 0.f;
    #pragma unroll
    for (int t = 0; t < 10; ++t) q += mw[g*10 + t] * sp[t];
    qs[g] = q;
  }
  float sc_own[R];
  #pragma unroll
  for (int rr = 0; rr < R; ++rr) {
    float sc = sv[rr][0]*qs[0] + sv[rr][1]*qs[1] + sv[rr][2]*qs[2]
             + sv[rr][3]*qs[3] + sv[rr][4]*qs[4];
    sc_own[rr] = sc;
    if (act[rr]) scb[st + slot + rr*T] = sc;
  }
  WSYNC();
  float mx = -1e30f;
  for (int jj = 0; jj < n; ++jj) mx = fmaxf(mx, scb[st + jj]);
  float e_own[R];
  #pragma unroll
  for (int rr = 0; rr < R; ++rr) e_own[rr] = __expf(sc_own[rr] - mx);
  WSYNC();
  #pragma unroll
  for (int rr = 0; rr < R; ++rr) if (act[rr]) scb[st + slot + rr*T] = e_own[rr];
  WSYNC();
  float sum = 0.f;
  for (int jj = 0; jj < n; ++jj) sum += scb[st + jj];
  float inv = 1.f / sum;
  float po[5] = {0,0,0,0,0};
  #pragma unroll
  for (int rr = 0; rr < R; ++rr) if (act[rr]) {
    float a = e_own[rr] * inv;
    #pragma unroll
    for (int g = 0; g < 5; ++g) po[g] += a * sv[rr][g];
  }
  #pragma unroll
  for (int off = 1; off < T; off <<= 1)
    #pragma unroll
    for (int g = 0; g < 5; ++g) po[g] += __shfl_xor(po[g], off);
  if (team < G && slot == 0) {
    #pragma unroll
    for (int g = 0; g < 5; ++g) catb[b*736 + BASE + g*G + team] = (f16)po[g];
  }
}

// prep: transpose weights to f16 [N][K] + build Mp[320][320] f16 (cols = d*62+i, k = g*62+j)
__global__ void wcvt_kernel(const float* __restrict__ w1, const float* __restrict__ w2,
                            const float* __restrict__ w3,
                            const float* __restrict__ adj, const float* __restrict__ lgcn_w,
                            f16* __restrict__ w1T, f16* __restrict__ w2T, f16* __restrict__ w3T,
                            f16* __restrict__ Mp)
{
  int i = blockIdx.x * 256 + threadIdx.x;
  if (i < 256*736) {
    int n = i / 736, k = i - n*736;
    w1T[i] = (f16)(k < 735 ? w1[k*256 + n] : 0.f);
    return;
  }
  int j = i - 256*736;
  if (j < 128*256) {
    int n = j >> 8, k = j & 255;
    w2T[j] = (f16)w2[k*128 + n];
    return;
  }
  int q = j - 128*256;
  if (q < 64*128) {
    int n = q >> 7, k = q & 127;
    w3T[q] = (f16)w3[k*64 + n];
    return;
  }
  int m = q - 64*128;
  if (m < 320*320) {
    int col = m / 320, k = m - col*320;
    float v = 0.f;
    if (col < 310 && k < 310) {
      int d = col / 62, ii = col - d*62;
      int g = k / 62,  jj = k - g*62;
      v = adj[ii*62 + jj] * lgcn_w[g*5 + d];
    }
    Mp[m] = (f16)v;
  }
}

// lgcn as GEMM: cat[b, 0:310] = x[b,:] @ Mp + lgcn_b   (64 samples/block, 4 waves)
__global__ __launch_bounds__(256) void gemm_h(
    const float* __restrict__ x, const f16* __restrict__ Mp,
    const float* __restrict__ lgcn_b, f16* __restrict__ catb)
{
  __shared__ __align__(16) f16 a_lds[64*320];   // 40 KB, chunk-swizzled; reused for D

  const int tid = threadIdx.x;
  const int wv = tid >> 6;
  const int lane = tid & 63;
  const int ln = lane & 15;
  const int kg = lane >> 4;
  const long b0 = (long)blockIdx.x * 64;

  const f16* mp[5];
  #pragma unroll
  for (int nc = 0; nc < 5; ++nc)
    mp[nc] = Mp + (size_t)(wv*80 + nc*16 + ln)*320 + kg*8;
  f16x8 bF[5], bN[5];
  #pragma unroll
  for (int nc = 0; nc < 5; ++nc) bF[nc] = *(const f16x8*)(mp[nc]);

  for (int rr = 0; rr < 16; ++rr) {
    int row = wv*16 + rr;
    if (lane < 8) {
      int c = 38 + (lane >> 2);
      *(unsigned*)((char*)a_lds + row*640 + ((c ^ (row & 7)) << 4) + (lane & 3)*4) = 0u;
    }
    const float* xr = x + (b0 + row)*310;
    for (int f = lane; f < 155; f += 64) {
      float2 v = *(const float2*)(xr + 2*f);
      int k = 2*f;
      int c = k >> 3;
      f16 h0 = (f16)v.x, h1 = (f16)v.y;
      unsigned u = (unsigned)*(unsigned short*)&h0 | ((unsigned)*(unsigned short*)&h1 << 16);
      *(unsigned*)((char*)a_lds + row*640 + ((c ^ (row & 7)) << 4) + (k & 7)*2) = u;
    }
  }
  __syncthreads();

  f32x4 zero = {0.f, 0.f, 0.f, 0.f};
  f32x4 acc[4][5];
  #pragma unroll
  for (int mr = 0; mr < 4; ++mr)
    #pragma unroll
    for (int nc = 0; nc < 5; ++nc) acc[mr][nc] = zero;

  for (int s = 0; s < 10; ++s) {
    if (s < 9) {
      #pragma unroll
      for (int nc = 0; nc < 5; ++nc) bN[nc] = *(const f16x8*)(mp[nc] + (s + 1)*32);
    }
    #pragma unroll
    for (int mr = 0; mr < 4; ++mr) {
      int r = mr*16 + ln;
      int c = s*4 + kg;
      f16x8 af = *(const f16x8*)((const char*)a_lds + r*640 + ((c ^ (r & 7)) << 4));
      #pragma unroll
      for (int nc = 0; nc < 5; ++nc)
        acc[mr][nc] = __builtin_amdgcn_mfma_f32_16x16x32_f16(af, bF[nc], acc[mr][nc], 0, 0, 0);
    }
    #pragma unroll
    for (int nc = 0; nc < 5; ++nc) bF[nc] = bN[nc];
  }

  __syncthreads();
  #pragma unroll
  for (int nc = 0; nc < 5; ++nc) {
    int n = wv*80 + nc*16 + ln;
    float bias = (n < 310) ? lgcn_b[n / 62] : 0.f;
    int c = n >> 3;
    #pragma unroll
    for (int mr = 0; mr < 4; ++mr) {
      #pragma unroll
      for (int ri = 0; ri < 4; ++ri) {
        int r = mr*16 + kg*4 + ri;
        f16 val = (f16)(acc[mr][nc][ri] + bias);
        *(f16*)((char*)a_lds + r*640 + ((c ^ (r & 7)) << 4) + (n & 7)*2) = val;
      }
    }
  }
  __syncthreads();
  for (int rr = 0; rr < 16; ++rr) {
    int row = wv*16 + rr;
    if (lane < 39) {
      int c = lane;
      f16x8 v = *(const f16x8*)((const char*)a_lds + row*640 + ((c ^ (row & 7)) << 4));
      *(f16x8*)(catb + (b0 + row)*736 + c*8) = v;
    }
  }
}

// per-sample front work (post-lgcn); one wave per sample, 4 samples/block.
// All post-staging sync is wave-local (WSYNC): each sample touched by exactly one wave.
__global__ __launch_bounds__(256, 5) void front2(
    const float* __restrict__ ca1_w1, const float* __restrict__ ca1_w2,
    const float* __restrict__ ca2_w1, const float* __restrict__ ca2_w2,
    const float* __restrict__ meso1_w, const float* __restrict__ meso2_w,
    const int* __restrict__ idx16, const int* __restrict__ idx7,
    f16* __restrict__ catb, float* __restrict__ outp, int B)
{
  __shared__ float h_s[4][560];     // [62][9] pad -> conflict-free (gcd(9,32)=1)
  __shared__ float sc_s[4][80];
  __shared__ float t_s[4][64];
  __shared__ float small_s[4][16];  // avg[5], mx[5], att1[5]
  __shared__ float v62_s[4][128];   // avg2[62] | mx2[62]
  __shared__ float mw_s[100];
  __shared__ float c1a_s[160];      // ca1_w1 [32][5]
  __shared__ float c1b_s[160];      // ca1_w2 [5][32]
  __shared__ f16  w1c_s[62*32];     // ca2_w1 transposed [i][o]
  __shared__ f16  w2c_s[32*64];     // ca2_w2 transposed [o][i pad 64]
  __shared__ int  idx16_s[73];
  __shared__ int  idx7_s[78];

  const int tid = threadIdx.x;
  const int w = tid >> 6;
  const int lane = tid & 63;
  const long b = (long)blockIdx.x * 4 + w;

  // ---- cooperative staging (once per block) ----
  if (tid < 100) mw_s[tid] = (tid < 50) ? meso1_w[tid] : meso2_w[tid - 50];
  if (tid < 160) { c1a_s[tid] = ca1_w1[tid]; c1b_s[tid] = ca1_w2[tid]; }
  if (tid < 73) idx16_s[tid] = idx16[tid];
  if (tid < 78) idx7_s[tid] = idx7[tid];
  for (int t = tid; t < 62*32; t += 256) {
    int i = t >> 5, o = t & 31;
    w1c_s[t] = (f16)ca2_w1[o*62 + i];
  }
  for (int t = tid; t < 62*32; t += 256) {
    int o = t / 62, i = t - o*62;
    w2c_s[o*64 + i] = (f16)ca2_w2[i*32 + o];
  }
  __syncthreads();

  // ---- h load (regs + LDS) ----
  float hv[5] = {0,0,0,0,0};
  if (lane < 62) {
    #pragma unroll
    for (int d = 0; d < 5; ++d) hv[d] = (float)catb[b*736 + d*62 + lane];
    #pragma unroll
    for (int d = 0; d < 5; ++d) h_s[w][lane*9 + d] = hv[d];
  }
  WSYNC();

  // ---- CA1 stats: 40 lanes (d = lane>>3, q = lane&7), reduce over q ----
  {
    int d = lane >> 3, q = lane & 7;
    float s = 0.f, m = -1e30f;
    if (d < 5) {
      #pragma unroll
      for (int e = 0; e < 8; ++e) {
        int i = q*8 + e;
        if (i < 62) { float v = h_s[w][i*9 + d]; s += v; m = fmaxf(m, v); }
      }
    }
    #pragma unroll
    for (int off = 1; off < 8; off <<= 1) {
      s += __shfl_xor(s, off);
      m = fmaxf(m, __shfl_xor(m, off));
    }
    if (d < 5 && q == 0) {
      small_s[w][d] = s * (1.f/62.f);
      small_s[w][5 + d] = m;
    }
  }
  WSYNC();
  // ---- CA1 mlp hidden (lane<32) ----
  if (lane < 32) {
    float ta = 0.f, tm = 0.f;
    #pragma unroll
    for (int d = 0; d < 5; ++d) {
      float wv = c1a_s[lane*5 + d];
      ta += small_s[w][d] * wv;
      tm += small_s[w][5 + d] * wv;
    }
    t_s[w][lane] = fmaxf(ta, 0.f);
    t_s[w][32 + lane] = fmaxf(tm, 0.f);
  }
  WSYNC();
  // ---- att1 (lane<5) ----
  if (lane < 5) {
    float sa = 0.f, sm = 0.f;
    #pragma unroll 4
    for (int o = 0; o < 32; ++o) {
      float wv = c1b_s[lane*32 + o];
      sa += t_s[w][o] * wv; sm += t_s[w][32 + o] * wv;
    }
    float a = 1.f / (1.f + __expf(-(sa + sm)));
    small_s[w][10 + lane] = a;
    outp[(long)B*64 + b*5 + lane] = a;
  }
  WSYNC();
  // ---- CA2 stats (lane<62, over d, from regs) ----
  float a1f[5];
  #pragma unroll
  for (int d = 0; d < 5; ++d) a1f[d] = 1.f + small_s[w][10 + d];
  if (lane < 62) {
    float s = 0.f, m = -1e30f;
    #pragma unroll
    for (int d = 0; d < 5; ++d) {
      float v = hv[d] * a1f[d];
      s += v; m = fmaxf(m, v);
    }
    v62_s[w][lane] = s * (1.f/5.f);
    v62_s[w][64 + lane] = m;
  }
  WSYNC();
  // ---- CA2 mlp hidden: all 64 lanes (half avg, half max) ----
  {
    int half = lane >> 5;
    int o = lane & 31;
    const float* src = &v62_s[w][half*64];
    float t = 0.f;
    #pragma unroll 2
    for (int i = 0; i < 62; ++i) t += src[i] * (float)w1c_s[i*32 + o];
    t_s[w][half*32 + o] = fmaxf(t, 0.f);
  }
  WSYNC();
  // ---- att2 (lane<62) + out_flat from regs ----
  if (lane < 62) {
    float sa = 0.f, sm = 0.f;
    #pragma unroll 4
    for (int o = 0; o < 32; ++o) {
      float wv = (float)w2c_s[o*64 + lane];
      sa += t_s[w][o] * wv; sm += t_s[w][32 + o] * wv;
    }
    float a2 = 1.f / (1.f + __expf(-(sa + sm)));
    outp[(long)B*69 + b*62 + lane] = a2;
    float f2 = 1.f + a2;
    #pragma unroll
    for (int d = 0; d < 5; ++d)
      catb[b*736 + 310 + d*62 + lane] = (f16)(hv[d] * a1f[d] * f2);
  }
  if (lane == 0) catb[b*736 + 735] = (f16)0.f;

  // ---- meso (h_s gathers are wave-local; already visible) ----
  meso_reg<4,16,3,620>(c_g16_st, c_g16_n, lane, b, h_s[w], idx16_s, mw_s, sc_s[w], catb);
  meso_reg<8,7,4,700>(c_g7_st, c_g7_n, lane, b, h_s[w], idx7_s, mw_s + 50, sc_s[w], catb);
}

// fused 3-layer MLP via f16 MFMA; 64 samples/block, 4 waves
__global__ __launch_bounds__(256) void mlp_mfma(
    const f16* __restrict__ cat,
    const f16* __restrict__ w1T, const f16* __restrict__ w2T, const f16* __restrict__ w3T,
    const float* __restrict__ b1, const float* __restrict__ g1, const float* __restrict__ be1,
    const float* __restrict__ m1, const float* __restrict__ v1,
    const float* __restrict__ b2, const float* __restrict__ g2, const float* __restrict__ be2,
    const float* __restrict__ m2, const float* __restrict__ v2,
    const float* __restrict__ b3, const float* __restrict__ g3, const float* __restrict__ be3,
    const float* __restrict__ m3, const float* __restrict__ v3,
    float* __restrict__ outp)
{
  __shared__ __align__(16) f16 a_lds[64*32];
  __shared__ __align__(16) f16 y1s[64*256];
  __shared__ __align__(16) f16 y2s[64*128];

  const int tid = threadIdx.x;
  const int wv = tid >> 6;
  const int lane = tid & 63;
  const int ln = lane & 15;
  const int kg = lane >> 4;
  const long b0 = (long)blockIdx.x * 64;

  f32x4 zero = {0.f, 0.f, 0.f, 0.f};
  f32x4 acc1[4][4];
  #pragma unroll
  for (int i = 0; i < 4; ++i)
    #pragma unroll
    for (int j = 0; j < 4; ++j) acc1[i][j] = zero;

  const int sr  = tid >> 2;
  const int scs = tid & 3;
  const int sdst = sr*64 + ((scs ^ ((sr >> 1) & 3)) << 4);
  const f16* aSrc = cat + (b0 + sr)*736 + scs*8;

  int aoff[4];
  #pragma unroll
  for (int mr = 0; mr < 4; ++mr) {
    int r = mr*16 + ln;
    aoff[mr] = r*64 + ((kg ^ ((r >> 1) & 3)) << 4);
  }

  const f16* w1p[4];
  #pragma unroll
  for (int nc = 0; nc < 4; ++nc)
    w1p[nc] = w1T + (size_t)(wv*64 + nc*16 + ln)*736 + kg*8;

  f16x8 bF[4], bN[4];
  #pragma unroll
  for (int nc = 0; nc < 4; ++nc) bF[nc] = *(const f16x8*)(w1p[nc]);
  f16x8 aReg = *(const f16x8*)(aSrc);
  f16x8 aRegN;

  for (int s = 0; s < 23; ++s) {
    __syncthreads();
    *(f16x8*)((char*)a_lds + sdst) = aReg;
    __syncthreads();
    if (s < 22) {
      aRegN = *(const f16x8*)(aSrc + (s + 1)*32);
      #pragma unroll
      for (int nc = 0; nc < 4; ++nc) bN[nc] = *(const f16x8*)(w1p[nc] + (s + 1)*32);
    }
    #pragma unroll
    for (int mr = 0; mr < 4; ++mr) {
      f16x8 af = *(const f16x8*)((const char*)a_lds + aoff[mr]);
      #pragma unroll
      for (int nc = 0; nc < 4; ++nc)
        acc1[mr][nc] = __builtin_amdgcn_mfma_f32_16x16x32_f16(af, bF[nc], acc1[mr][nc], 0, 0, 0);
    }
    aReg = aRegN;
    #pragma unroll
    for (int nc = 0; nc < 4; ++nc) bF[nc] = bN[nc];
  }

  #pragma unroll
  for (int nc = 0; nc < 4; ++nc) {
    int n = wv*64 + nc*16 + ln;
    float sc = g1[n] * rsqrtf(v1[n] + BN_EPS);
    float bm = b1[n] - m1[n];
    float bo = be1[n];
    int c = n >> 3;
    #pragma unroll
    for (int mr = 0; mr < 4; ++mr) {
      #pragma unroll
      for (int ri = 0; ri < 4; ++ri) {
        int r = mr*16 + kg*4 + ri;
        float y = lrelu((acc1[mr][nc][ri] + bm)*sc + bo);
        int off = r*512 + ((c ^ (r & 7)) << 4) + ((n & 7) << 1);
        *(f16*)((char*)y1s + off) = (f16)y;
      }
    }
  }
  __syncthreads();

  f32x4 acc2[4][2];
  #pragma unroll
  for (int i = 0; i < 4; ++i) { acc2[i][0] = zero; acc2[i][1] = zero; }
  const f16* w2p[2];
  #pragma unroll
  for (int nc = 0; nc < 2; ++nc)
    w2p[nc] = w2T + (size_t)(wv*32 + nc*16 + ln)*256 + kg*8;

  #pragma unroll
  for (int s2 = 0; s2 < 8; ++s2) {
    f16x8 b2f[2];
    #pragma unroll
    for (int nc = 0; nc < 2; ++nc) b2f[nc] = *(const f16x8*)(w2p[nc] + s2*32);
    #pragma unroll
    for (int mr = 0; mr < 4; ++mr) {
      int r = mr*16 + ln;
      int c = s2*4 + kg;
      f16x8 af = *(const f16x8*)((const char*)y1s + r*512 + ((c ^ (r & 7)) << 4));
      #pragma unroll
      for (int nc = 0; nc < 2; ++nc)
        acc2[mr][nc] = __builtin_amdgcn_mfma_f32_16x16x32_f16(af, b2f[nc], acc2[mr][nc], 0, 0, 0);
    }
  }
  #pragma unroll
  for (int nc = 0; nc < 2; ++nc) {
    int n = wv*32 + nc*16 + ln;
    float sc = g2[n] * rsqrtf(v2[n] + BN_EPS);
    float bm = b2[n] - m2[n];
    float bo = be2[n];
    int c = n >> 3;
    #pragma unroll
    for (int mr = 0; mr < 4; ++mr) {
      #pragma unroll
      for (int ri = 0; ri < 4; ++ri) {
        int r = mr*16 + kg*4 + ri;
        float y = lrelu((acc2[mr][nc][ri] + bm)*sc + bo);
        int off = r*256 + ((c ^ (r & 7)) << 4) + ((n & 7) << 1);
        *(f16*)((char*)y2s + off) = (f16)y;
      }
    }
  }
  __syncthreads();

  f32x4 acc3[4];
  #pragma unroll
  for (int i = 0; i < 4; ++i) acc3[i] = zero;
  const f16* w3p = w3T + (size_t)(wv*16 + ln)*128 + kg*8;

  #pragma unroll
  for (int s3 = 0; s3 < 4; ++s3) {
    f16x8 bf = *(const f16x8*)(w3p + s3*32);
    #pragma unroll
    for (int mr = 0; mr < 4; ++mr) {
      int r = mr*16 + ln;
      int c = s3*4 + kg;
      f16x8 af = *(const f16x8*)((const char*)y2s + r*256 + ((c ^ (r & 7)) << 4));
      acc3[mr] = __builtin_amdgcn_mfma_f32_16x16x32_f16(af, bf, acc3[mr], 0, 0, 0);
    }
  }
  {
    int n = wv*16 + ln;
    float sc = g3[n] * rsqrtf(v3[n] + BN_EPS);
    float bm = b3[n] - m3[n];
    float bo = be3[n];
    #pragma unroll
    for (int mr = 0; mr < 4; ++mr) {
      #pragma unroll
      for (int ri = 0; ri < 4; ++ri) {
        int r = mr*16 + kg*4 + ri;
        float y = lrelu((acc3[mr][ri] + bm)*sc + bo);
        outp[(size_t)(b0 + r)*64 + n] = y;
      }
    }
  }
}

extern "C" void kernel_launch(void* const* d_in, const int* in_sizes, int n_in,
                              void* d_out, int out_size, void* d_ws, size_t ws_size,
                              hipStream_t stream) {
  const float* x       = (const float*)d_in[0];
  const float* adj     = (const float*)d_in[1];
  const float* lgcn_w  = (const float*)d_in[2];
  const float* lgcn_b  = (const float*)d_in[3];
  const float* ca1_w1  = (const float*)d_in[4];
  const float* ca1_w2  = (const float*)d_in[5];
  const float* ca2_w1  = (const float*)d_in[6];
  const float* ca2_w2  = (const float*)d_in[7];
  const float* meso1_w = (const float*)d_in[8];
  const float* meso2_w = (const float*)d_in[9];
  const int*   idx16   = (const int*)d_in[10];
  const int*   idx7    = (const int*)d_in[11];
  const float* w1 = (const float*)d_in[12];
  const float* b1 = (const float*)d_in[13];
  const float* w2 = (const float*)d_in[14];
  const float* b2 = (const float*)d_in[15];
  const float* w3 = (const float*)d_in[16];
  const float* b3 = (const float*)d_in[17];
  const float* g1 = (const float*)d_in[18];
  const float* be1= (const float*)d_in[19];
  const float* m1 = (const float*)d_in[20];
  const float* v1 = (const float*)d_in[21];
  const float* g2 = (const float*)d_in[22];
  const float* be2= (const float*)d_in[23];
  const float* m2 = (const float*)d_in[24];
  const float* v2 = (const float*)d_in[25];
  const float* g3 = (const float*)d_in[26];
  const float* be3= (const float*)d_in[27];
  const float* m3 = (const float*)d_in[28];
  const float* v3 = (const float*)d_in[29];

  const int B = in_sizes[0] / 310;

  // ws: cat f16 [B][736] | w1T [256][736] | w2T [128][256] | w3T [64][128] | Mp [320][320]
  const size_t catBytes = (size_t)B * 736 * sizeof(f16);
  char* wsc = (char*)d_ws;
  f16* catb = (f16*)wsc;
  f16* w1T  = (f16*)(wsc + catBytes);
  f16* w2T  = (f16*)(wsc + catBytes + 256*736*sizeof(f16));
  f16* w3T  = (f16*)(wsc + catBytes + (256*736 + 128*256)*sizeof(f16));
  f16* Mp   = (f16*)(wsc + catBytes + (256*736 + 128*256 + 64*128)*sizeof(f16));
  const size_t need = catBytes + (256*736 + 128*256 + 64*128 + 320*320)*sizeof(f16);
  if (ws_size < need) return;  // fail visibly

  const int prepElems = 256*736 + 128*256 + 64*128 + 320*320;
  wcvt_kernel<<<(prepElems + 255)/256, 256, 0, stream>>>(w1, w2, w3, adj, lgcn_w,
                                                         w1T, w2T, w3T, Mp);
  gemm_h<<<B/64, 256, 0, stream>>>(x, Mp, lgcn_b, catb);
  front2<<<B/4, 256, 0, stream>>>(ca1_w1, ca1_w2, ca2_w1, ca2_w2, meso1_w, meso2_w,
                                  idx16, idx7, catb, (float*)d_out, B);
  mlp_mfma<<<B/64, 256, 0, stream>>>(catb, w1T, w2T, w3T,
                                     b1, g1, be1, m1, v1,
                                     b2, g2, be2, m2, v2,
                                     b3, g3, be3, m3, v3, (float*)d_out);
}